// Round 1
// 9507.533 us; speedup vs baseline: 1.7127x; 1.7127x over previous
//
#include <hip/hip_runtime.h>

typedef _Float16 h16;
typedef __attribute__((ext_vector_type(2))) _Float16 h16x2;
typedef __attribute__((ext_vector_type(4))) _Float16 h16x4;
typedef __attribute__((ext_vector_type(8))) _Float16 h16x8;
typedef __attribute__((ext_vector_type(4))) float    f32x4;
typedef __attribute__((ext_vector_type(4))) unsigned u32x4;
typedef __attribute__((ext_vector_type(2))) unsigned u32x2;

constexpr int B_  = 16;
constexpr int T_  = 2048;
constexpr int D_  = 512;
constexpr int H_  = 512;
constexpr int O_  = 256;
constexpr int G4_ = 2048;           // 4*H
constexpr int BT_ = B_ * T_;

__device__ __forceinline__ float sigm(float x)   { return 1.f / (1.f + __expf(-x)); }
__device__ __forceinline__ float tanh_f(float x) { return 1.f - 2.f / (1.f + __expf(2.f * x)); }

// coherent (L1/L2-bypassing) 16B load — served from L3/mem, never a stale local line
__device__ __forceinline__ u32x4 load_cg16(const unsigned* p) {
  u32x4 r;
  asm volatile("global_load_dwordx4 %0, %1, off sc0 sc1" : "=v"(r) : "v"(p) : "memory");
  return r;
}

// ---------------- prep: fp32 x -> fp16 X, and mask bits ----------------
__global__ void k_prep_x(const float* __restrict__ x, h16* __restrict__ Xh,
                         unsigned* __restrict__ maskbits) {
  const int row = blockIdx.x;              // b*T + t
  const int b = row >> 11, t = row & 2047;
  const float2* xr = (const float2*)(x + (size_t)row * D_);
  float2 v = xr[threadIdx.x];
  h16x2 hv = { (h16)v.x, (h16)v.y };
  *(h16x2*)(Xh + (size_t)row * D_ + threadIdx.x * 2) = hv;
  float s = v.x + v.y;
  #pragma unroll
  for (int off = 32; off > 0; off >>= 1) s += __shfl_down(s, off, 64);
  __shared__ float red[4];
  const int lane = threadIdx.x & 63, wv = threadIdx.x >> 6;
  if (lane == 0) red[wv] = s;
  __syncthreads();
  if (threadIdx.x == 0) {
    float tot = red[0] + red[1] + red[2] + red[3];
    if (tot != 0.f) atomicOr(&maskbits[t], 1u << b);
  }
}

// ---------------- fp32 -> fp16 convert (weights) ----------------
__global__ void k_cvt(const float* __restrict__ s, h16* __restrict__ d, int n4) {
  int i = blockIdx.x * 256 + threadIdx.x;
  if (i < n4) {
    f32x4 v = ((const f32x4*)s)[i];
    h16x4 o = { (h16)v.x, (h16)v.y, (h16)v.z, (h16)v.w };
    ((h16x4*)d)[i] = o;
  }
}

__global__ void k_bias(const float* __restrict__ a, const float* __restrict__ b,
                       float* __restrict__ o, int n) {
  int i = blockIdx.x * 256 + threadIdx.x;
  if (i < n) o[i] = a[i] + b[i];
}

// ---------------- GEMM: C[m][n] = sum_k A[m,k]*B[n,k]  (both K-contiguous) ----------------
__global__ __launch_bounds__(256, 2)
void k_gemm(const h16* __restrict__ A, const h16* __restrict__ Bm, h16* __restrict__ C,
            int M, int N, int K) {
  __shared__ h16 As[128 * 32];
  __shared__ h16 Bs[128 * 32];
  const int tiles_n = N >> 7;
  const int tm = blockIdx.x / tiles_n, tn = blockIdx.x % tiles_n;
  const int tid = threadIdx.x, lane = tid & 63, wv = tid >> 6;
  const int wm = (wv >> 1) * 64, wn = (wv & 1) * 64;
  const int ml = lane & 15, qd = lane >> 4;
  f32x4 acc[4][4] = {};
  const h16* Arow = A + (size_t)(tm * 128) * K;
  const h16* Brow = Bm + (size_t)(tn * 128) * K;
  for (int kt = 0; kt < K; kt += 32) {
    __syncthreads();
    #pragma unroll
    for (int p = 0; p < 2; ++p) {
      int ch = tid + p * 256;
      int r = ch >> 2, qq = ch & 3;
      int sidx = r * 4 + ((qq + r) & 3);     // XOR swizzle to spread banks
      *(h16x8*)(As + sidx * 8) = *(const h16x8*)(Arow + (size_t)r * K + kt + qq * 8);
      *(h16x8*)(Bs + sidx * 8) = *(const h16x8*)(Brow + (size_t)r * K + kt + qq * 8);
    }
    __syncthreads();
    h16x8 af[4], bfv[4];
    #pragma unroll
    for (int i = 0; i < 4; ++i) {
      int ra = wm + i * 16 + ml;
      af[i]  = *(const h16x8*)(As + (ra * 4 + ((qd + ra) & 3)) * 8);
      int rb = wn + i * 16 + ml;
      bfv[i] = *(const h16x8*)(Bs + (rb * 4 + ((qd + rb) & 3)) * 8);
    }
    #pragma unroll
    for (int i = 0; i < 4; ++i)
      #pragma unroll
      for (int j = 0; j < 4; ++j)
        acc[i][j] = __builtin_amdgcn_mfma_f32_16x16x32_f16(af[i], bfv[j], acc[i][j], 0, 0, 0);
  }
  const int colb = lane & 15, rowq = (lane >> 4) * 4;
  #pragma unroll
  for (int i = 0; i < 4; ++i)
    #pragma unroll
    for (int j = 0; j < 4; ++j) {
      int row0 = tm * 128 + wm + i * 16 + rowq;
      int col  = tn * 128 + wn + j * 16 + colb;
      #pragma unroll
      for (int r = 0; r < 4; ++r)
        C[(size_t)(row0 + r) * N + col] = (h16)acc[i][j][r];
    }
}

// ---------------- fused 2-layer persistent recurrence (merged WGs) ----------------
// 32 WGs; WG g owns 16-column slice g of BOTH layers.
// Round r (r = 0..T):  compute h0^r (layer0, needs h0^{r-1}) and h1^{r-1}
// (layer1, needs h0^{r-1} and h1^{r-2}).  One combined message per round:
//   M_r = {h0^r, h1^{r-1}}, 16 samples x 1024 cols, word = (tag r+1)<<16 | fp16.
//   slot(M_r) = (r+1)&3.  Round r gathers M_{r-1} (slot r&3, tag r).
// Sync: per-WG flag[g] = r+1, stored AFTER the publish-draining __syncthreads
// (vmcnt(0) before s_barrier => data at L3 before flag).  Consumers poll the
// 32 flags with 32 lanes, then do ONE coalesced sc0/sc1 dwordx4 gather with
// embedded-tag verification (retry loop = safety net only).
// Safety: writing M_r (slot (r+1)&3) clobbers M_{r-4}, which every WG consumed
// at round r-3; being at round r implies everyone finished round r-1 >= r-3's
// gather, so no backpressure is needed.
__global__ __launch_bounds__(256, 1)
void k_lstm2m(const h16* __restrict__ G,
              const h16* __restrict__ Whh0,
              const h16* __restrict__ Wih1,
              const h16* __restrict__ Whh1,
              const float* __restrict__ bias0,
              const float* __restrict__ bias1,
              const unsigned* __restrict__ maskbits,
              unsigned* ring, unsigned* flags, float* hT_out) {
  const int g = blockIdx.x;                 // 0..31, column-slice owner
  const int tid = threadIdx.x, lane = tid & 63, w = tid >> 6;   // w = gate
  const int nl = lane & 15, qd = lane >> 4;

  __shared__ h16 Hst0[16 * 520];            // gathered h0^{r-1}  [sample][col]
  __shared__ h16 Hst1[16 * 520];            // gathered h1^{r-2}
  __shared__ float ge0[4][16][18];          // [gate][col-in-slice][sample]
  __shared__ float ge1[4][16][18];
  __shared__ float c0s[16][16], c1s[16][16];
  __shared__ unsigned msh[2];               // mask[r], mask[r-1]

  // resident weights: rows w*512 + g*16 + nl, k = kt*32 + qd*8 .. +7
  h16x8 a_hh0[16], a_ih1[16], a_hh1[16];
  {
    const size_t ro = (size_t)(w * 512 + g * 16 + nl) * 512 + qd * 8;
    const h16* p0 = Whh0 + ro;
    const h16* p1 = Wih1 + ro;
    const h16* p2 = Whh1 + ro;
    #pragma unroll
    for (int kt = 0; kt < 16; ++kt) {
      a_hh0[kt] = *(const h16x8*)(p0 + kt * 32);
      a_ih1[kt] = *(const h16x8*)(p1 + kt * 32);
      a_hh1[kt] = *(const h16x8*)(p2 + kt * 32);
    }
  }
  float b0v[4], b1v[4];
  #pragma unroll
  for (int rr = 0; rr < 4; ++rr) {
    b0v[rr] = bias0[w * 512 + g * 16 + qd * 4 + rr];
    b1v[rr] = bias1[w * 512 + g * 16 + qd * 4 + rr];
  }

  for (int i = tid; i < 16 * 520; i += 256) { Hst0[i] = (h16)0.f; Hst1[i] = (h16)0.f; }
  c0s[tid >> 4][tid & 15] = 0.f;
  c1s[tid >> 4][tid & 15] = 0.f;
  __syncthreads();

  // gather destination: thread owns 4 consecutive cols of every sample
  h16* dstb = (tid < 128) ? (Hst0 + tid * 4) : (Hst1 + tid * 4 - 512);
  const int jj = tid >> 4, n = tid & 15;    // update-phase coords

  for (int r = 0; r <= T_; ++r) {
    h16x4 gv = {};
    if (r < T_)   // issue early: HBM latency hides under flag poll
      gv = *(const h16x4*)(G + ((size_t)nl * T_ + r) * G4_ + w * 512 + g * 16 + qd * 4);

    if (r > 0) {
      // ---- light flag poll (32 lanes only) ----
      if (tid < 32) {
        const unsigned* fp = flags + tid * 16;
        while (__hip_atomic_load(fp, __ATOMIC_RELAXED, __HIP_MEMORY_SCOPE_AGENT) < (unsigned)r)
          __builtin_amdgcn_s_sleep(1);
      }
      if (tid == 0) { msh[0] = (r < T_) ? maskbits[r] : 0u; msh[1] = maskbits[r - 1]; }
      __syncthreads();                      // flags seen -> data is at L3

      // ---- single-pass coalesced gather with tag verify ----
      const unsigned tagw = (unsigned)r << 16;
      const unsigned* sb = ring + (size_t)(r & 3) * 16384 + tid * 4;
      for (;;) {
        u32x4 v[16];
        #pragma unroll
        for (int j = 0; j < 16; ++j) v[j] = load_cg16(sb + j * 1024);
        asm volatile("s_waitcnt vmcnt(0)" ::: "memory");
        __builtin_amdgcn_sched_barrier(0);
        unsigned bad = 0;
        #pragma unroll
        for (int j = 0; j < 16; ++j)
          bad |= (v[j].x ^ tagw) | (v[j].y ^ tagw) | (v[j].z ^ tagw) | (v[j].w ^ tagw);
        #pragma unroll
        for (int j = 0; j < 16; ++j) {
          u32x2 pk;
          pk.x = (v[j].x & 0xffffu) | (v[j].y << 16);
          pk.y = (v[j].z & 0xffffu) | (v[j].w << 16);
          *(u32x2*)(dstb + (size_t)j * 520) = pk;   // 8B/lane, stride-2 banks: conflict-free
        }
        if (__syncthreads_and((bad & 0xffff0000u) == 0)) break;
        __builtin_amdgcn_s_sleep(1);
      }
    } else {
      if (tid == 0) { msh[0] = maskbits[0]; msh[1] = 0u; }
      // gate barrier below publishes msh
    }

    // ---- MFMA: three independent 16-chains (b0 shared by two of them) ----
    f32x4 acc0 = {}, acc1a = {}, acc1b = {};
    if (r > 0) {
      const h16* h0p = Hst0 + nl * 520 + qd * 8;
      const h16* h1p = Hst1 + nl * 520 + qd * 8;
      #pragma unroll
      for (int kt = 0; kt < 16; ++kt) {
        h16x8 bb0 = *(const h16x8*)(h0p + kt * 32);
        if (r < T_) acc0 = __builtin_amdgcn_mfma_f32_16x16x32_f16(a_hh0[kt], bb0, acc0, 0, 0, 0);
        acc1a = __builtin_amdgcn_mfma_f32_16x16x32_f16(a_ih1[kt], bb0, acc1a, 0, 0, 0);
        h16x8 bb1 = *(const h16x8*)(h1p + kt * 32);
        acc1b = __builtin_amdgcn_mfma_f32_16x16x32_f16(a_hh1[kt], bb1, acc1b, 0, 0, 0);
      }
    }

    // ---- activations (wave-uniform gate type) ----
    if (r < T_) {
      #pragma unroll
      for (int rr = 0; rr < 4; ++rr) {
        float pre = acc0[rr] + b0v[rr] + (float)gv[rr];
        ge0[w][qd * 4 + rr][nl] = (w == 2) ? tanh_f(pre) : sigm(pre);
      }
    }
    if (r > 0) {
      #pragma unroll
      for (int rr = 0; rr < 4; ++rr) {
        float pre = acc1a[rr] + acc1b[rr] + b1v[rr];
        ge1[w][qd * 4 + rr][nl] = (w == 2) ? tanh_f(pre) : sigm(pre);
      }
    }
    __syncthreads();

    // ---- state update + publish ----
    {
      const unsigned mcur = msh[0], mprev = msh[1];
      unsigned* slot = ring + (size_t)((r + 1) & 3) * 16384 + (size_t)n * 1024 + g * 16 + jj;
      if (r < T_) {
        float iv = ge0[0][jj][n], fv = ge0[1][jj][n];
        float gg = ge0[2][jj][n], ov = ge0[3][jj][n];
        bool m = (mcur >> n) & 1u;
        float c_old = c0s[jj][n];
        float c_new = m ? (fv * c_old + iv * gg) : c_old;
        c0s[jj][n] = c_new;
        float h_old = (float)Hst0[n * 520 + g * 16 + jj];
        float h_new = m ? (ov * tanh_f(c_new)) : h_old;
        h16 hh = (h16)h_new; unsigned short hb; __builtin_memcpy(&hb, &hh, 2);
        __hip_atomic_store(slot, ((unsigned)(r + 1) << 16) | hb,
                           __ATOMIC_RELAXED, __HIP_MEMORY_SCOPE_AGENT);
      }
      float h1_new = 0.f;
      if (r > 0) {
        float iv = ge1[0][jj][n], fv = ge1[1][jj][n];
        float gg = ge1[2][jj][n], ov = ge1[3][jj][n];
        bool m = (mprev >> n) & 1u;
        float c_old = c1s[jj][n];
        float c_new = m ? (fv * c_old + iv * gg) : c_old;
        c1s[jj][n] = c_new;
        float h_old = (float)Hst1[n * 520 + g * 16 + jj];
        h1_new = m ? (ov * tanh_f(c_new)) : h_old;
      }
      if (r < T_) {
        h16 hh = (h16)h1_new; unsigned short hb; __builtin_memcpy(&hb, &hh, 2);
        __hip_atomic_store(slot + 512, ((unsigned)(r + 1) << 16) | hb,
                           __ATOMIC_RELAXED, __HIP_MEMORY_SCOPE_AGENT);
      } else {
        hT_out[(size_t)n * H_ + g * 16 + jj] = h1_new;
      }
    }
    __syncthreads();   // drains publishes (vmcnt 0) + protects LDS for next round
    if (tid == 0 && r < T_)
      __hip_atomic_store(flags + g * 16, (unsigned)(r + 1),
                         __ATOMIC_RELAXED, __HIP_MEMORY_SCOPE_AGENT);
  }
}

// ---------------- final FC: out = hT @ Wfc^T + bfc (fp32) ----------------
__global__ void k_fc(const float* __restrict__ hT, const float* __restrict__ Wfc,
                     const float* __restrict__ bfc, float* __restrict__ out) {
  const int b = blockIdx.x;
  __shared__ float hs[H_];
  for (int i = threadIdx.x; i < H_; i += 256) hs[i] = hT[(size_t)b * H_ + i];
  __syncthreads();
  const int o = threadIdx.x;
  const float* wr = Wfc + (size_t)o * H_;
  float s = bfc[o];
  for (int k = 0; k < H_; k += 4) {
    f32x4 w4 = *(const f32x4*)(wr + k);
    s += hs[k] * w4.x + hs[k + 1] * w4.y + hs[k + 2] * w4.z + hs[k + 3] * w4.w;
  }
  out[(size_t)b * O_ + o] = s;
}

extern "C" void kernel_launch(void* const* d_in, const int* in_sizes, int n_in,
                              void* d_out, int out_size, void* d_ws, size_t ws_size,
                              hipStream_t stream) {
  const float* x    = (const float*)d_in[0];
  const float* Wih0 = (const float*)d_in[1];
  const float* Whh0 = (const float*)d_in[2];
  const float* bih0 = (const float*)d_in[3];
  const float* bhh0 = (const float*)d_in[4];
  const float* Wih1 = (const float*)d_in[5];
  const float* Whh1 = (const float*)d_in[6];
  const float* bih1 = (const float*)d_in[7];
  const float* bhh1 = (const float*)d_in[8];
  const float* Wfc  = (const float*)d_in[9];
  const float* bfc  = (const float*)d_in[10];

  char* base = (char*)d_ws;
  size_t off = 0;
  auto alloc = [&](size_t bytes) -> void* {
    void* r = base + off;
    off = (off + bytes + 255) & ~(size_t)255;
    return r;
  };
  h16* Xh   = (h16*)alloc((size_t)BT_ * D_ * 2);
  h16* Gbuf = (h16*)alloc((size_t)BT_ * G4_ * 2);
  h16* Wb0  = (h16*)alloc((size_t)G4_ * D_ * 2);
  h16* Wb1  = (h16*)alloc((size_t)G4_ * H_ * 2);   // Whh0
  h16* Wb2  = (h16*)alloc((size_t)G4_ * H_ * 2);   // Wih1
  h16* Wb3  = (h16*)alloc((size_t)G4_ * H_ * 2);   // Whh1
  float* bs0 = (float*)alloc(G4_ * 4);
  float* bs1 = (float*)alloc(G4_ * 4);
  unsigned* maskbits = (unsigned*)alloc(T_ * 4);
  unsigned* ring  = (unsigned*)alloc((size_t)4 * 16 * 1024 * 4);   // 4 slots x 16 samples x 1024 cols
  unsigned* flags = (unsigned*)alloc(32 * 16 * 4);                 // 1 flag / WG, 64B spaced
  float* hT = (float*)alloc((size_t)B_ * H_ * 4);

  hipMemsetAsync(maskbits, 0, T_ * 4, stream);
  hipMemsetAsync(ring, 0, (size_t)4 * 16 * 1024 * 4, stream);
  hipMemsetAsync(flags, 0, 32 * 16 * 4, stream);
  k_prep_x<<<BT_, 256, 0, stream>>>(x, Xh, maskbits);
  const int wn4 = G4_ * D_ / 4;
  k_cvt<<<(wn4 + 255) / 256, 256, 0, stream>>>(Wih0, Wb0, wn4);
  k_cvt<<<(wn4 + 255) / 256, 256, 0, stream>>>(Whh0, Wb1, wn4);
  k_cvt<<<(wn4 + 255) / 256, 256, 0, stream>>>(Wih1, Wb2, wn4);
  k_cvt<<<(wn4 + 255) / 256, 256, 0, stream>>>(Whh1, Wb3, wn4);
  k_bias<<<(G4_ + 255) / 256, 256, 0, stream>>>(bih0, bhh0, bs0, G4_);
  k_bias<<<(G4_ + 255) / 256, 256, 0, stream>>>(bih1, bhh1, bs1, G4_);

  k_gemm<<<(BT_ / 128) * (G4_ / 128), 256, 0, stream>>>(Xh, Wb0, Gbuf, BT_, G4_, D_);
  k_lstm2m<<<32, 256, 0, stream>>>(Gbuf, Wb1, Wb2, Wb3, bs0, bs1, maskbits,
                                   ring, flags, hT);
  k_fc<<<B_, 256, 0, stream>>>(hT, Wfc, bfc, (float*)d_out);
}

// Round 2
// 7555.989 us; speedup vs baseline: 2.1550x; 1.2583x over previous
//
#include <hip/hip_runtime.h>

typedef _Float16 h16;
typedef __attribute__((ext_vector_type(2))) _Float16 h16x2;
typedef __attribute__((ext_vector_type(4))) _Float16 h16x4;
typedef __attribute__((ext_vector_type(8))) _Float16 h16x8;
typedef __attribute__((ext_vector_type(4))) float    f32x4;
typedef __attribute__((ext_vector_type(4))) unsigned u32x4;
typedef __attribute__((ext_vector_type(2))) unsigned u32x2;

constexpr int B_  = 16;
constexpr int T_  = 2048;
constexpr int D_  = 512;
constexpr int H_  = 512;
constexpr int O_  = 256;
constexpr int G4_ = 2048;           // 4*H
constexpr int BT_ = B_ * T_;

__device__ __forceinline__ float sigm(float x)   { return 1.f / (1.f + __expf(-x)); }
__device__ __forceinline__ float tanh_f(float x) { return 1.f - 2.f / (1.f + __expf(2.f * x)); }

// coherent (L1/L2-bypassing) 16B load — always served from a coherent point
__device__ __forceinline__ u32x4 load_cg16(const unsigned* p) {
  u32x4 r;
  asm volatile("global_load_dwordx4 %0, %1, off sc0 sc1" : "=v"(r) : "v"(p) : "memory");
  return r;
}

// ---------------- prep: fp32 x -> fp16 X, and mask bits ----------------
__global__ void k_prep_x(const float* __restrict__ x, h16* __restrict__ Xh,
                         unsigned* __restrict__ maskbits) {
  const int row = blockIdx.x;              // b*T + t
  const int b = row >> 11, t = row & 2047;
  const float2* xr = (const float2*)(x + (size_t)row * D_);
  float2 v = xr[threadIdx.x];
  h16x2 hv = { (h16)v.x, (h16)v.y };
  *(h16x2*)(Xh + (size_t)row * D_ + threadIdx.x * 2) = hv;
  float s = v.x + v.y;
  #pragma unroll
  for (int off = 32; off > 0; off >>= 1) s += __shfl_down(s, off, 64);
  __shared__ float red[4];
  const int lane = threadIdx.x & 63, wv = threadIdx.x >> 6;
  if (lane == 0) red[wv] = s;
  __syncthreads();
  if (threadIdx.x == 0) {
    float tot = red[0] + red[1] + red[2] + red[3];
    if (tot != 0.f) atomicOr(&maskbits[t], 1u << b);
  }
}

// ---------------- fp32 -> fp16 convert (weights) ----------------
__global__ void k_cvt(const float* __restrict__ s, h16* __restrict__ d, int n4) {
  int i = blockIdx.x * 256 + threadIdx.x;
  if (i < n4) {
    f32x4 v = ((const f32x4*)s)[i];
    h16x4 o = { (h16)v.x, (h16)v.y, (h16)v.z, (h16)v.w };
    ((h16x4*)d)[i] = o;
  }
}

__global__ void k_bias(const float* __restrict__ a, const float* __restrict__ b,
                       float* __restrict__ o, int n) {
  int i = blockIdx.x * 256 + threadIdx.x;
  if (i < n) o[i] = a[i] + b[i];
}

// ---------------- GEMM: C[m][n] = sum_k A[m,k]*B[n,k]  (both K-contiguous) ----------------
__global__ __launch_bounds__(256, 2)
void k_gemm(const h16* __restrict__ A, const h16* __restrict__ Bm, h16* __restrict__ C,
            int M, int N, int K) {
  __shared__ h16 As[128 * 32];
  __shared__ h16 Bs[128 * 32];
  const int tiles_n = N >> 7;
  const int tm = blockIdx.x / tiles_n, tn = blockIdx.x % tiles_n;
  const int tid = threadIdx.x, lane = tid & 63, wv = tid >> 6;
  const int wm = (wv >> 1) * 64, wn = (wv & 1) * 64;
  const int ml = lane & 15, qd = lane >> 4;
  f32x4 acc[4][4] = {};
  const h16* Arow = A + (size_t)(tm * 128) * K;
  const h16* Brow = Bm + (size_t)(tn * 128) * K;
  for (int kt = 0; kt < K; kt += 32) {
    __syncthreads();
    #pragma unroll
    for (int p = 0; p < 2; ++p) {
      int ch = tid + p * 256;
      int r = ch >> 2, qq = ch & 3;
      int sidx = r * 4 + ((qq + r) & 3);     // XOR swizzle to spread banks
      *(h16x8*)(As + sidx * 8) = *(const h16x8*)(Arow + (size_t)r * K + kt + qq * 8);
      *(h16x8*)(Bs + sidx * 8) = *(const h16x8*)(Brow + (size_t)r * K + kt + qq * 8);
    }
    __syncthreads();
    h16x8 af[4], bfv[4];
    #pragma unroll
    for (int i = 0; i < 4; ++i) {
      int ra = wm + i * 16 + ml;
      af[i]  = *(const h16x8*)(As + (ra * 4 + ((qd + ra) & 3)) * 8);
      int rb = wn + i * 16 + ml;
      bfv[i] = *(const h16x8*)(Bs + (rb * 4 + ((qd + rb) & 3)) * 8);
    }
    #pragma unroll
    for (int i = 0; i < 4; ++i)
      #pragma unroll
      for (int j = 0; j < 4; ++j)
        acc[i][j] = __builtin_amdgcn_mfma_f32_16x16x32_f16(af[i], bfv[j], acc[i][j], 0, 0, 0);
  }
  const int colb = lane & 15, rowq = (lane >> 4) * 4;
  #pragma unroll
  for (int i = 0; i < 4; ++i)
    #pragma unroll
    for (int j = 0; j < 4; ++j) {
      int row0 = tm * 128 + wm + i * 16 + rowq;
      int col  = tn * 128 + wn + j * 16 + colb;
      #pragma unroll
      for (int r = 0; r < 4; ++r)
        C[(size_t)(row0 + r) * N + col] = (h16)acc[i][j][r];
    }
}

// ---------------- fused 2-layer persistent recurrence (merged WGs) ----------------
// 32 WGs; WG g owns 16-column slice g of BOTH layers.
// Round r (0..T): compute h0^r (needs h0^{r-1}) and h1^{r-1} (needs h0^{r-1},
// h1^{r-2}).  One combined message M_r = {h0^r, h1^{r-1}} (16 samples x 1024
// cols, word = (tag r+1)<<16 | fp16), published into slot (r+1)&3.
// Sync = the data itself: round r spins on slot r&3 until all 16 of the lane's
// dwordx4 lines carry tag r (per-lane exit; one coalesced reload per retry),
// then unpacks ONCE and hits a workgroup barrier.  No flags, no producer
// drain: detection latency == data-arrival latency.
// Ring safety (depth 4): publishing M_r requires having gathered M_{r-1},
// which requires ALL WGs to have published M_{r-1} => every WG is past its
// round r-2 gather; M_r's slot clobbers M_{r-4}, whose only readers were at
// round r-3.  Margin 2 rounds.
// Barriers/round: 2 (post-gather, act->update).  Hst double-buffered by r&1.
__global__ __launch_bounds__(256, 1)
void k_lstm2m(const h16* __restrict__ G,
              const h16* __restrict__ Whh0,
              const h16* __restrict__ Wih1,
              const h16* __restrict__ Whh1,
              const float* __restrict__ bias0,
              const float* __restrict__ bias1,
              const unsigned* __restrict__ maskbits,
              unsigned* ring, float* hT_out) {
  const int g = blockIdx.x;                 // 0..31, column-slice owner
  const int tid = threadIdx.x, lane = tid & 63, w = tid >> 6;   // w = gate
  const int nl = lane & 15, qd = lane >> 4;

  __shared__ h16 Hst0[2][16 * 520];         // gathered h0^{r-1}, dbuf by r&1
  __shared__ h16 Hst1[2][16 * 520];         // gathered h1^{r-2}
  __shared__ float ge0[4][16][18];          // [gate][col-in-slice][sample]
  __shared__ float ge1[4][16][18];
  __shared__ float c0s[16][17], c1s[16][17];

  // resident weights: rows w*512 + g*16 + nl, k = kt*32 + qd*8 .. +7
  h16x8 a_hh0[16], a_ih1[16], a_hh1[16];
  {
    const size_t ro = (size_t)(w * 512 + g * 16 + nl) * 512 + qd * 8;
    const h16* p0 = Whh0 + ro;
    const h16* p1 = Wih1 + ro;
    const h16* p2 = Whh1 + ro;
    #pragma unroll
    for (int kt = 0; kt < 16; ++kt) {
      a_hh0[kt] = *(const h16x8*)(p0 + kt * 32);
      a_ih1[kt] = *(const h16x8*)(p1 + kt * 32);
      a_hh1[kt] = *(const h16x8*)(p2 + kt * 32);
    }
  }
  float b0v[4], b1v[4];
  #pragma unroll
  for (int rr = 0; rr < 4; ++rr) {
    b0v[rr] = bias0[w * 512 + g * 16 + qd * 4 + rr];
    b1v[rr] = bias1[w * 512 + g * 16 + qd * 4 + rr];
  }

  for (int i = tid; i < 16 * 520; i += 256) {
    Hst0[0][i] = (h16)0.f; Hst0[1][i] = (h16)0.f;
    Hst1[0][i] = (h16)0.f; Hst1[1][i] = (h16)0.f;
  }
  const int jj = tid & 15, n = tid >> 4;    // update-phase coords (coalesced publish)
  c0s[jj][n] = 0.f;
  c1s[jj][n] = 0.f;
  __syncthreads();

  for (int r = 0; r <= T_; ++r) {
    const int buf = r & 1;
    h16x4 gv = {};
    if (r < T_)   // issue early: HBM latency hides under the spin
      gv = *(const h16x4*)(G + ((size_t)nl * T_ + r) * G4_ + w * 512 + g * 16 + qd * 4);
    const unsigned mcur  = (r < T_) ? maskbits[r] : 0u;   // uniform -> s_load
    const unsigned mprev = (r > 0) ? maskbits[r - 1] : 0u;

    if (r > 0) {
      // ---- tagged-data spin: per-lane exit, one coalesced reload/retry ----
      const unsigned tagw = (unsigned)r << 16;
      const unsigned* sb = ring + ((size_t)(r & 3) << 14) + tid * 4;
      h16* dst = (tid < 128) ? (Hst0[buf] + tid * 4) : (Hst1[buf] + (tid - 128) * 4);
      bool done = false;
      while (!done) {
        u32x4 v[16];
        #pragma unroll
        for (int j = 0; j < 16; ++j) v[j] = load_cg16(sb + j * 1024);
        asm volatile("s_waitcnt vmcnt(0)" ::: "memory");
        __builtin_amdgcn_sched_barrier(0);
        unsigned bad = 0;
        #pragma unroll
        for (int j = 0; j < 16; ++j)
          bad |= (v[j].x ^ tagw) | (v[j].y ^ tagw) | (v[j].z ^ tagw) | (v[j].w ^ tagw);
        if ((bad & 0xffff0000u) == 0) {
          #pragma unroll
          for (int j = 0; j < 16; ++j) {
            u32x2 pk;
            pk.x = (v[j].x & 0xffffu) | (v[j].y << 16);
            pk.y = (v[j].z & 0xffffu) | (v[j].w << 16);
            *(u32x2*)(dst + (size_t)j * 520) = pk;   // 8B/lane, 2-way banks: free
          }
          done = true;
        }
      }
      __syncthreads();                      // Hst[buf] fully gathered
    }

    // ---- MFMA: three independent 16-chains (bb0 shared by two) ----
    f32x4 acc0 = {}, acc1a = {}, acc1b = {};
    if (r > 0) {
      const h16* h0p = Hst0[buf] + nl * 520 + qd * 8;
      const h16* h1p = Hst1[buf] + nl * 520 + qd * 8;
      #pragma unroll
      for (int kt = 0; kt < 16; ++kt) {
        h16x8 bb0 = *(const h16x8*)(h0p + kt * 32);
        if (r < T_) acc0 = __builtin_amdgcn_mfma_f32_16x16x32_f16(a_hh0[kt], bb0, acc0, 0, 0, 0);
        acc1a = __builtin_amdgcn_mfma_f32_16x16x32_f16(a_ih1[kt], bb0, acc1a, 0, 0, 0);
        h16x8 bb1 = *(const h16x8*)(h1p + kt * 32);
        acc1b = __builtin_amdgcn_mfma_f32_16x16x32_f16(a_hh1[kt], bb1, acc1b, 0, 0, 0);
      }
    }

    // ---- activations (wave-uniform gate type) ----
    if (r < T_) {
      #pragma unroll
      for (int rr = 0; rr < 4; ++rr) {
        float pre = acc0[rr] + b0v[rr] + (float)gv[rr];
        ge0[w][qd * 4 + rr][nl] = (w == 2) ? tanh_f(pre) : sigm(pre);
      }
    }
    if (r > 0) {
      #pragma unroll
      for (int rr = 0; rr < 4; ++rr) {
        float pre = acc1a[rr] + acc1b[rr] + b1v[rr];
        ge1[w][qd * 4 + rr][nl] = (w == 2) ? tanh_f(pre) : sigm(pre);
      }
    }
    __syncthreads();

    // ---- state update + coalesced publish (jj fastest across lanes) ----
    {
      unsigned* slot = ring + (((size_t)((r + 1) & 3)) << 14) + (size_t)n * 1024 + g * 16 + jj;
      if (r < T_) {
        float iv = ge0[0][jj][n], fv = ge0[1][jj][n];
        float gg = ge0[2][jj][n], ov = ge0[3][jj][n];
        bool m = (mcur >> n) & 1u;
        float c_old = c0s[jj][n];
        float c_new = m ? (fv * c_old + iv * gg) : c_old;
        c0s[jj][n] = c_new;
        float h_old = (float)Hst0[buf][n * 520 + g * 16 + jj];
        float h_new = m ? (ov * tanh_f(c_new)) : h_old;
        h16 hh = (h16)h_new; unsigned short hb; __builtin_memcpy(&hb, &hh, 2);
        __hip_atomic_store(slot, ((unsigned)(r + 1) << 16) | hb,
                           __ATOMIC_RELAXED, __HIP_MEMORY_SCOPE_AGENT);
      }
      float h1_new = 0.f;
      if (r > 0) {
        float iv = ge1[0][jj][n], fv = ge1[1][jj][n];
        float gg = ge1[2][jj][n], ov = ge1[3][jj][n];
        bool m = (mprev >> n) & 1u;
        float c_old = c1s[jj][n];
        float c_new = m ? (fv * c_old + iv * gg) : c_old;
        c1s[jj][n] = c_new;
        float h_old = (float)Hst1[buf][n * 520 + g * 16 + jj];
        h1_new = m ? (ov * tanh_f(c_new)) : h_old;
      }
      if (r < T_) {
        h16 hh = (h16)h1_new; unsigned short hb; __builtin_memcpy(&hb, &hh, 2);
        __hip_atomic_store(slot + 512, ((unsigned)(r + 1) << 16) | hb,
                           __ATOMIC_RELAXED, __HIP_MEMORY_SCOPE_AGENT);
      } else {
        hT_out[(size_t)n * H_ + g * 16 + jj] = h1_new;
      }
    }
    // no end barrier: next round's post-gather barrier orders ge/c/Hst reuse
  }
}

// ---------------- final FC: out = hT @ Wfc^T + bfc (fp32) ----------------
__global__ void k_fc(const float* __restrict__ hT, const float* __restrict__ Wfc,
                     const float* __restrict__ bfc, float* __restrict__ out) {
  const int b = blockIdx.x;
  __shared__ float hs[H_];
  for (int i = threadIdx.x; i < H_; i += 256) hs[i] = hT[(size_t)b * H_ + i];
  __syncthreads();
  const int o = threadIdx.x;
  const float* wr = Wfc + (size_t)o * H_;
  float s = bfc[o];
  for (int k = 0; k < H_; k += 4) {
    f32x4 w4 = *(const f32x4*)(wr + k);
    s += hs[k] * w4.x + hs[k + 1] * w4.y + hs[k + 2] * w4.z + hs[k + 3] * w4.w;
  }
  out[(size_t)b * O_ + o] = s;
}

extern "C" void kernel_launch(void* const* d_in, const int* in_sizes, int n_in,
                              void* d_out, int out_size, void* d_ws, size_t ws_size,
                              hipStream_t stream) {
  const float* x    = (const float*)d_in[0];
  const float* Wih0 = (const float*)d_in[1];
  const float* Whh0 = (const float*)d_in[2];
  const float* bih0 = (const float*)d_in[3];
  const float* bhh0 = (const float*)d_in[4];
  const float* Wih1 = (const float*)d_in[5];
  const float* Whh1 = (const float*)d_in[6];
  const float* bih1 = (const float*)d_in[7];
  const float* bhh1 = (const float*)d_in[8];
  const float* Wfc  = (const float*)d_in[9];
  const float* bfc  = (const float*)d_in[10];

  char* base = (char*)d_ws;
  size_t off = 0;
  auto alloc = [&](size_t bytes) -> void* {
    void* r = base + off;
    off = (off + bytes + 255) & ~(size_t)255;
    return r;
  };
  h16* Xh   = (h16*)alloc((size_t)BT_ * D_ * 2);
  h16* Gbuf = (h16*)alloc((size_t)BT_ * G4_ * 2);
  h16* Wb0  = (h16*)alloc((size_t)G4_ * D_ * 2);
  h16* Wb1  = (h16*)alloc((size_t)G4_ * H_ * 2);   // Whh0
  h16* Wb2  = (h16*)alloc((size_t)G4_ * H_ * 2);   // Wih1
  h16* Wb3  = (h16*)alloc((size_t)G4_ * H_ * 2);   // Whh1
  float* bs0 = (float*)alloc(G4_ * 4);
  float* bs1 = (float*)alloc(G4_ * 4);
  unsigned* maskbits = (unsigned*)alloc(T_ * 4);
  unsigned* ring  = (unsigned*)alloc((size_t)4 * 16 * 1024 * 4);   // 4 slots x 16 samples x 1024 cols
  float* hT = (float*)alloc((size_t)B_ * H_ * 4);

  hipMemsetAsync(maskbits, 0, T_ * 4, stream);
  hipMemsetAsync(ring, 0, (size_t)4 * 16 * 1024 * 4, stream);
  k_prep_x<<<BT_, 256, 0, stream>>>(x, Xh, maskbits);
  const int wn4 = G4_ * D_ / 4;
  k_cvt<<<(wn4 + 255) / 256, 256, 0, stream>>>(Wih0, Wb0, wn4);
  k_cvt<<<(wn4 + 255) / 256, 256, 0, stream>>>(Whh0, Wb1, wn4);
  k_cvt<<<(wn4 + 255) / 256, 256, 0, stream>>>(Wih1, Wb2, wn4);
  k_cvt<<<(wn4 + 255) / 256, 256, 0, stream>>>(Whh1, Wb3, wn4);
  k_bias<<<(G4_ + 255) / 256, 256, 0, stream>>>(bih0, bhh0, bs0, G4_);
  k_bias<<<(G4_ + 255) / 256, 256, 0, stream>>>(bih1, bhh1, bs1, G4_);

  k_gemm<<<(BT_ / 128) * (G4_ / 128), 256, 0, stream>>>(Xh, Wb0, Gbuf, BT_, G4_, D_);
  k_lstm2m<<<32, 256, 0, stream>>>(Gbuf, Wb1, Wb2, Wb3, bs0, bs1, maskbits,
                                   ring, hT);
  k_fc<<<B_, 256, 0, stream>>>(hT, Wfc, bfc, (float*)d_out);
}